// Round 10
// baseline (391.190 us; speedup 1.0000x reference)
//
#include <hip/hip_runtime.h>

#define N_NODES 20000
#define HID 64
#define NSTEPS 6
#define NSLICE 8
#define SLICE_SZ (N_NODES / NSLICE)  // 2500
#define SUBB 64                      // sub-chunks per slice (phase 2)
#define NBLK (NSLICE * SUBB)         // 512 blocks for hist/scatter
#define TBLK ((N_NODES + 63) / 64)   // 313 transpose blocks (fused into scatter)
#define NB1 2048                     // blocks for count/bucket phase (8/CU: latency hiding)
#define CBLK ((N_NODES + 255) / 256) // 79 colscan/scan2 blocks
#define MAGIC 13422                  // floor(d*13422 / 2^25) == d/2500 for d < 20000

typedef _Float16 h8_t __attribute__((ext_vector_type(8)));
typedef float f4_t __attribute__((ext_vector_type(4)));  // native vec for nontemporal st
typedef unsigned long long u64;

union U16H { unsigned short u; _Float16 h; };
union U4H8 { uint4 u; _Float16 h[8]; };
union U2H8 { u64 q[2]; _Float16 h[8]; };

__device__ __forceinline__ _Float16 us_as_h(unsigned short s) { U16H u; u.u = s; return u.h; }
__device__ __forceinline__ unsigned short h_as_us(_Float16 h) { U16H u; u.h = h; return u.u; }

// L1-bypass gather: agent-scope relaxed loads emit global_load_dwordx2 sc0 (skip L1).
// Experiment R10: tests whether the step's gather ceiling is the L1 miss-tracking
// (MSHR) table — bypass path may sustain more outstanding requests.
__device__ __forceinline__ void gath_bypass(const _Float16* p, U2H8& out) {
    const u64* q = (const u64*)p;
    out.q[0] = __hip_atomic_load(q, __ATOMIC_RELAXED, __HIP_MEMORY_SCOPE_AGENT);
    out.q[1] = __hip_atomic_load(q + 1, __ATOMIC_RELAXED, __HIP_MEMORY_SCOPE_AGENT);
}

__device__ __forceinline__ int slice_of(int d) {
    return (int)(((unsigned)d * (unsigned)MAGIC) >> 25);
}
__device__ __forceinline__ float softplusf_(float x) {
    return (x > 0.f) ? (x + log1pf(expf(-x))) : log1pf(expf(x));
}
__device__ __forceinline__ float sigmoidf_(float x) {
    return 1.f / (1.f + expf(-x));
}

// ---------------- P0: per-(block,slice) edge counts ----------------
__global__ __launch_bounds__(256) void count8_kernel(const int* __restrict__ edst,
                                                     int* __restrict__ gcnt, int TE) {
    __shared__ int lh[8];
    int bk = blockIdx.x;
    int lane = threadIdx.x & 63;
    if (threadIdx.x < 8) lh[threadIdx.x] = 0;
    __syncthreads();
    int chunk = ((TE + NB1 - 1) / NB1 + 255) & ~255;
    int lo = bk * chunk;
    int hi = min(lo + chunk, TE);
    int my = 0;
    int i = lo + (int)threadIdx.x;
    bool act = i < hi;
    int d = 0;
    if (act) d = __builtin_nontemporal_load(edst + i);
    for (int ii = 0; ii < chunk; ii += 256) {
        int inext = i + 256;
        bool actn = inext < hi;
        int dn = 0;
        if (actn) dn = __builtin_nontemporal_load(edst + inext);  // prefetch next iter
        int s = act ? slice_of(d) : -1;
#pragma unroll
        for (int q = 0; q < 8; ++q) {
            unsigned long long b = __ballot(s == q);
            if (lane == q) my += (int)__popcll(b);
        }
        i = inext; act = actn; d = dn;
    }
    if (lane < 8) atomicAdd(&lh[lane], my);
    __syncthreads();
    if (threadIdx.x < 8) gcnt[bk * 8 + threadIdx.x] = lh[threadIdx.x];
}

// ---------------- P0b: scan gcnt -> blkoff + bbase[9]; fused prep constants ----------------
__global__ __launch_bounds__(256) void scan8_kernel(const int* __restrict__ gcnt,
                                                    int* __restrict__ blkoff,
                                                    int* __restrict__ bbase,
                                                    const float* __restrict__ g_logits,
                                                    const float* __restrict__ alpha_logits,
                                                    const int* __restrict__ cell_idx,
                                                    const float* __restrict__ cell_emb,
                                                    const float* __restrict__ W2,
                                                    const float* __restrict__ b2,
                                                    float* __restrict__ gsign,
                                                    float* __restrict__ alph,
                                                    float* __restrict__ cell_dot) {
    __shared__ int psum[8][33];
    int tid = threadIdx.x;
    int s = tid >> 5, g = tid & 31;
    const int per = NB1 / 32;  // 64
    int sum = 0;
    for (int b = g * per; b < (g + 1) * per; ++b) sum += gcnt[b * 8 + s];
    psum[s][g] = sum;
    __syncthreads();
    if (tid < 8) {
        int run = 0;
        for (int i = 0; i < 32; ++i) { int v = psum[tid][i]; psum[tid][i] = run; run += v; }
        psum[tid][32] = run;
    }
    __syncthreads();
    int run = psum[s][g];
    for (int b = g * per; b < (g + 1) * per; ++b) {
        blkoff[b * 8 + s] = run;
        run += gcnt[b * 8 + s];
    }
    if (tid == 0) {
        int acc = 0;
        bbase[0] = 0;
        for (int q = 0; q < 8; ++q) { acc += psum[q][32]; bbase[q + 1] = acc; }
    }
    // fused prep (independent outputs)
    if (tid < 64) {
        if (tid < 6) gsign[tid] = ((tid & 1) ? -1.f : 1.f) * softplusf_(g_logits[tid]);
        if (tid < NSTEPS) alph[tid] = sigmoidf_(alpha_logits[tid]);
        int ci = cell_idx[tid];
        float acc = b2[0];
        for (int hh = 0; hh < HID; ++hh) acc = fmaf(cell_emb[ci * HID + hh], W2[hh], acc);
        cell_dot[tid] = acc;
    }
}

// ---------------- P1: bucket edges by slice; SoA {meta, coef} ----------------
__global__ __launch_bounds__(256) void bucket_kernel(const int* __restrict__ esrc,
                                                     const int* __restrict__ edst,
                                                     const float* __restrict__ eval,
                                                     const float* __restrict__ gsign,
                                                     const int* __restrict__ blkoff,
                                                     const int* __restrict__ bbase,
                                                     int* __restrict__ bucketm,
                                                     int* __restrict__ bucketc,
                                                     int E, int TE) {
    __shared__ int lcur[8];
    int bk = blockIdx.x;
    int lane = threadIdx.x & 63;
    if (threadIdx.x < 8) lcur[threadIdx.x] = bbase[threadIdx.x] + blkoff[bk * 8 + threadIdx.x];
    __syncthreads();
    int chunk = ((TE + NB1 - 1) / NB1 + 255) & ~255;
    int lo = bk * chunk;
    int hi = min(lo + chunk, TE);
    int i = lo + (int)threadIdx.x;
    bool act = i < hi;
    int d = 0, sv = 0;
    float ev = 0.f;
    if (act) {
        d  = __builtin_nontemporal_load(edst + i);
        sv = __builtin_nontemporal_load(esrc + i);
        ev = __builtin_nontemporal_load(eval + i);
    }
    for (int ii = 0; ii < chunk; ii += 256) {
        // issue next iteration's loads before consuming current (hide stream latency)
        int inext = i + 256;
        bool actn = inext < hi;
        int dn = 0, svn = 0;
        float evn = 0.f;
        if (actn) {
            dn  = __builtin_nontemporal_load(edst + inext);
            svn = __builtin_nontemporal_load(esrc + inext);
            evn = __builtin_nontemporal_load(eval + inext);
        }
        int s = -1, meta = 0, cb = 0;
        if (act) {
            s = slice_of(d);
            int dl = d - s * SLICE_SZ;
            meta = sv | (dl << 16);
            int r = (i >= E) + (i >= 2 * E) + (i >= 3 * E) + (i >= 4 * E) + (i >= 5 * E);
            cb = __float_as_int(gsign[r] * ev);
        }
        int pos = 0;
#pragma unroll
        for (int q = 0; q < 8; ++q) {
            unsigned long long b = __ballot(s == q);
            if (b) {
                int leader = (int)__ffsll(b) - 1;
                int base = 0;
                if (lane == leader) base = atomicAdd(&lcur[q], (int)__popcll(b));
                base = __shfl(base, leader);
                if (s == q) pos = base + (int)__popcll(b & ((1ull << lane) - 1ull));
            }
        }
        if (act) {
            bucketm[pos] = meta;
            bucketc[pos] = cb;
        }
        i = inext; act = actn; d = dn; sv = svn; ev = evn;
    }
}

// ---------------- P2: per-(slice,sub) LDS histogram from the bucket (dense meta) --------
__global__ __launch_bounds__(256) void hist2db_kernel(const int* __restrict__ bucketm,
                                                      const int* __restrict__ bbase,
                                                      int* __restrict__ blkcnt) {
    __shared__ int lh[SLICE_SZ];
    int bk = blockIdx.x;
    int slice = bk & (NSLICE - 1);
    int sub = bk >> 3;
    for (int b = threadIdx.x; b < SLICE_SZ; b += 256) lh[b] = 0;
    __syncthreads();
    int lo = bbase[slice];
    int total = bbase[slice + 1] - lo;
    int chunk = ((total + SUBB - 1) / SUBB + 255) & ~255;
    int beg = lo + sub * chunk;
    int end = min(beg + chunk, lo + total);
    for (int i = beg + (int)threadIdx.x; i < end; i += 256) {
        int meta = __builtin_nontemporal_load(bucketm + i);
        atomicAdd(&lh[((unsigned)meta) >> 16], 1);
    }
    __syncthreads();
    int* out = blkcnt + (size_t)(slice * SUBB + sub) * SLICE_SZ;
    for (int b = threadIdx.x; b < SLICE_SZ; b += 256) out[b] = lh[b];
}

// ---------------- P3a: per-bin prefix across sub-blocks + per-block group sums ----------------
__global__ __launch_bounds__(256) void colscan_kernel(int* __restrict__ blkcnt,
                                                      int* __restrict__ counts,
                                                      int* __restrict__ blksum) {
    int n = blockIdx.x * 256 + threadIdx.x;
    int run = 0;
    if (n < N_NODES) {
        int slice = n / SLICE_SZ, bin = n % SLICE_SZ;
        size_t base = (size_t)slice * SUBB * SLICE_SZ + bin;
#pragma unroll 8
        for (int s = 0; s < SUBB; ++s) {
            size_t idx = base + (size_t)s * SLICE_SZ;
            int t = blkcnt[idx];
            blkcnt[idx] = run;
            run += t;
        }
        counts[n] = run;
    }
    // fused: block sum of padded group counts -> blksum[blockIdx.x]
    int g = (n < N_NODES) ? ((run + 7) >> 3) : 0;
#pragma unroll
    for (int st = 1; st < 64; st <<= 1) g += __shfl_xor(g, st, 64);
    __shared__ int wsum[4];
    if ((threadIdx.x & 63) == 0) wsum[threadIdx.x >> 6] = g;
    __syncthreads();
    if (threadIdx.x == 0) blksum[blockIdx.x] = wsum[0] + wsum[1] + wsum[2] + wsum[3];
}

// ---------------- P3b: parallel scan -> grp_ptr + surgical eg pad-zeroing ----------------
__global__ __launch_bounds__(256) void scan2_kernel(const int* __restrict__ counts,
                                                    const int* __restrict__ blksum,
                                                    int* __restrict__ grp_ptr,
                                                    unsigned* __restrict__ eg, int n) {
    int b = blockIdx.x;
    int tid = threadIdx.x, lane = tid & 63, wid = tid >> 6;
    int i = b * 256 + tid;
    int c = (i < n) ? counts[i] : 0;
    int v = (c + 7) >> 3;  // groups for this node
    int x = v;
#pragma unroll
    for (int st = 1; st < 64; st <<= 1) {
        int t = __shfl_up(x, st, 64);
        if (lane >= st) x += t;
    }
    __shared__ int wsum[4];
    if (lane == 63) wsum[wid] = x;
    // global offset: sum of blksum[l < b], redundant per wave (CBLK=79 < 128)
    int s = ((lane < b) ? blksum[lane] : 0) +
            ((lane + 64 < b) ? blksum[lane + 64] : 0);
#pragma unroll
    for (int st = 1; st < 64; st <<= 1) s += __shfl_xor(s, st, 64);
    __syncthreads();
    int woff = s;
    if (wid > 0) woff += wsum[0];
    if (wid > 1) woff += wsum[1];
    if (wid > 2) woff += wsum[2];
    int off = woff + x - v;  // exclusive
    if (i < n) {
        grp_ptr[i] = off;
        // zero ONLY the pad slots of this node's last group (<=7 entries);
        // step kernels never read past grp_ptr[i+1] so nothing else needs zeroing
        unsigned* base = eg + (size_t)off * 8;
        int slots = v * 8;
        for (int p = c; p < slots; ++p) base[p] = 0u;
    }
    if (i == n - 1) grp_ptr[n] = off + v;
}

// ---------------- P4: placement into 8-edge groups; fused u-transpose ----------------
// Group g: eg[8g + s] = src | (coef_f16 << 16), s=0..7. Pad slots zeroed by scan2.
// NOTE: uh must NOT alias buckets — transpose blocks run concurrently with
// scatter blocks inside this single launch.
__global__ __launch_bounds__(256) void scatter2b_kernel(const int* __restrict__ bucketm,
                                                        const int* __restrict__ bucketc,
                                                        const int* __restrict__ bbase,
                                                        const int* __restrict__ grp_ptr,
                                                        const int* __restrict__ blkcnt,
                                                        unsigned* __restrict__ eg,
                                                        const float* __restrict__ u_raw,
                                                        _Float16* __restrict__ uh) {
    __shared__ float smem[64 * 65];  // union: lbase (10 KB) | transpose tile (16.6 KB)
    int bk = blockIdx.x;
    if (bk >= NBLK) {
        // --- transpose section: u_raw [64, N] -> uh [N, 64] (f16) ---
        float(*tile)[65] = (float(*)[65])smem;
        int c0 = (bk - NBLK) * 64;
        int tx = threadIdx.x & 63, ty = threadIdx.x >> 6;
#pragma unroll
        for (int i = 0; i < 16; ++i) {
            int c = c0 + tx;
            tile[ty + i * 4][tx] = (c < N_NODES) ? u_raw[(size_t)(ty + i * 4) * N_NODES + c] : 0.f;
        }
        __syncthreads();
#pragma unroll
        for (int i = 0; i < 16; ++i) {
            int c = c0 + ty + i * 4;
            if (c < N_NODES) {
                float v = tile[tx][ty + i * 4];
                uh[(size_t)c * 64 + tx] = (_Float16)v;
            }
        }
        return;
    }
    int* lbase = (int*)smem;
    int slice = bk & (NSLICE - 1);
    int sub = bk >> 3;
    int lo_n = slice * SLICE_SZ;
    const int* boff = blkcnt + (size_t)(slice * SUBB + sub) * SLICE_SZ;
    for (int b = threadIdx.x; b < SLICE_SZ; b += 256)
        lbase[b] = grp_ptr[lo_n + b] * 8 + boff[b];
    __syncthreads();
    int lo = bbase[slice];
    int total = bbase[slice + 1] - lo;
    int chunk = ((total + SUBB - 1) / SUBB + 255) & ~255;
    int beg = lo + sub * chunk;
    int end = min(beg + chunk, lo + total);
    for (int i = beg + (int)threadIdx.x; i < end; i += 256) {
        int meta = __builtin_nontemporal_load(bucketm + i);
        float cf = __int_as_float(__builtin_nontemporal_load(bucketc + i));
        int pos = atomicAdd(&lbase[((unsigned)meta) >> 16], 1);
        eg[pos] = (unsigned)(meta & 0xFFFF) | ((unsigned)h_as_us((_Float16)cf) << 16);
    }
}

// ---------------- propagation step: 8 edges/gather, 4-group pipeline, L1-BYPASS gathers --
// R9 structure (334 us best) with ONE change: h gathers use agent-scope (sc0) loads,
// bypassing L1. Theory: gathers are L1-miss-concurrency (MSHR) bound — ~33 outstanding
// lines/CU at 350cyc L2 latency = measured 7.5 TB/s. Bypass path may sustain more.
// eg entry loads stay CACHED (cross-step L2 reuse; R6: nt cost +28us).
// Depth-2 pipelining refuted twice (R2 +11us, R8 +18us) — consistent with MSHR bound.
__global__ __launch_bounds__(256) void step_kernel(const _Float16* __restrict__ h_in,
                                                   const _Float16* __restrict__ h0,
                                                   _Float16* __restrict__ h_out,
                                                   float* __restrict__ hF,
                                                   const int* __restrict__ grp_ptr,
                                                   const unsigned* __restrict__ eg,
                                                   const float* __restrict__ alph,
                                                   int k, int last) {
    int lane = threadIdx.x & 63;
    int node = blockIdx.x * 4 + (threadIdx.x >> 6);
    if (node >= N_NODES) return;
    int gb = __builtin_amdgcn_readfirstlane(grp_ptr[node]);
    int ge = __builtin_amdgcn_readfirstlane(grp_ptr[node + 1]);
    int sub8 = lane >> 3;
    const _Float16* hbase = h_in + (lane & 7) * 8;
    const unsigned* ep = eg + sub8;
    float acc[8] = {0.f, 0.f, 0.f, 0.f, 0.f, 0.f, 0.f, 0.f};
    int g = gb;
    unsigned e0, e1, e2, e3;
    if (g + 4 <= ge) {
        e0 = ep[(size_t)g * 8];
        e1 = ep[(size_t)g * 8 + 8];
        e2 = ep[(size_t)g * 8 + 16];
        e3 = ep[(size_t)g * 8 + 24];
    }
    for (; g + 8 <= ge; g += 4) {
        // gathers for current quad (L1-bypass, 2x8B agent loads each)
        U2H8 v0, v1, v2, v3;
        gath_bypass(hbase + (e0 & 0xFFFFu) * 64, v0);
        gath_bypass(hbase + (e1 & 0xFFFFu) * 64, v1);
        gath_bypass(hbase + (e2 & 0xFFFFu) * 64, v2);
        gath_bypass(hbase + (e3 & 0xFFFFu) * 64, v3);
        // prefetch next quad's entries (independent of gathers)
        unsigned f0 = ep[(size_t)(g + 4) * 8];
        unsigned f1 = ep[(size_t)(g + 4) * 8 + 8];
        unsigned f2 = ep[(size_t)(g + 4) * 8 + 16];
        unsigned f3 = ep[(size_t)(g + 4) * 8 + 24];
        float c0 = (float)us_as_h((unsigned short)(e0 >> 16));
        float c1 = (float)us_as_h((unsigned short)(e1 >> 16));
        float c2 = (float)us_as_h((unsigned short)(e2 >> 16));
        float c3 = (float)us_as_h((unsigned short)(e3 >> 16));
#pragma unroll
        for (int j = 0; j < 8; ++j) acc[j] = fmaf((float)v0.h[j], c0, acc[j]);
#pragma unroll
        for (int j = 0; j < 8; ++j) acc[j] = fmaf((float)v1.h[j], c1, acc[j]);
#pragma unroll
        for (int j = 0; j < 8; ++j) acc[j] = fmaf((float)v2.h[j], c2, acc[j]);
#pragma unroll
        for (int j = 0; j < 8; ++j) acc[j] = fmaf((float)v3.h[j], c3, acc[j]);
        e0 = f0; e1 = f1; e2 = f2; e3 = f3;
    }
    if (g + 4 <= ge) {  // final full quad (entries already in registers)
        U2H8 v0, v1, v2, v3;
        gath_bypass(hbase + (e0 & 0xFFFFu) * 64, v0);
        gath_bypass(hbase + (e1 & 0xFFFFu) * 64, v1);
        gath_bypass(hbase + (e2 & 0xFFFFu) * 64, v2);
        gath_bypass(hbase + (e3 & 0xFFFFu) * 64, v3);
        float c0 = (float)us_as_h((unsigned short)(e0 >> 16));
        float c1 = (float)us_as_h((unsigned short)(e1 >> 16));
        float c2 = (float)us_as_h((unsigned short)(e2 >> 16));
        float c3 = (float)us_as_h((unsigned short)(e3 >> 16));
#pragma unroll
        for (int j = 0; j < 8; ++j) acc[j] = fmaf((float)v0.h[j], c0, acc[j]);
#pragma unroll
        for (int j = 0; j < 8; ++j) acc[j] = fmaf((float)v1.h[j], c1, acc[j]);
#pragma unroll
        for (int j = 0; j < 8; ++j) acc[j] = fmaf((float)v2.h[j], c2, acc[j]);
#pragma unroll
        for (int j = 0; j < 8; ++j) acc[j] = fmaf((float)v3.h[j], c3, acc[j]);
        g += 4;
    }
    for (; g < ge; ++g) {
        unsigned e = ep[(size_t)g * 8];
        U2H8 v;
        gath_bypass(hbase + (e & 0xFFFFu) * 64, v);
        float c = (float)us_as_h((unsigned short)(e >> 16));
#pragma unroll
        for (int j = 0; j < 8; ++j) acc[j] = fmaf((float)v.h[j], c, acc[j]);
    }
    // reduce edge slots: lanes {c, c+8, ..., c+56} share a batch octet
#pragma unroll
    for (int st = 8; st < 64; st <<= 1) {
#pragma unroll
        for (int j = 0; j < 8; ++j) acc[j] += __shfl_xor(acc[j], st, 64);
    }
    if (lane < 8) {
        float a = alph[k];
        int base = node * 64 + lane * 8;
        U4H8 hv;
        hv.u = *(const uint4*)(h0 + base);  // h0 in f16 (uh)
        float om = 1.f - a;
        float r0 = fmaf(a, (float)hv.h[0], om * acc[0]);
        float r1 = fmaf(a, (float)hv.h[1], om * acc[1]);
        float r2 = fmaf(a, (float)hv.h[2], om * acc[2]);
        float r3 = fmaf(a, (float)hv.h[3], om * acc[3]);
        float r4 = fmaf(a, (float)hv.h[4], om * acc[4]);
        float r5 = fmaf(a, (float)hv.h[5], om * acc[5]);
        float r6 = fmaf(a, (float)hv.h[6], om * acc[6]);
        float r7 = fmaf(a, (float)hv.h[7], om * acc[7]);
        if (last) {
            // hF is written once, read once (decode) — keep it out of L2
            f4_t o0 = {r0, r1, r2, r3};
            f4_t o1 = {r4, r5, r6, r7};
            __builtin_nontemporal_store(o0, (f4_t*)(hF + base));
            __builtin_nontemporal_store(o1, (f4_t*)(hF + base + 4));
        } else {
            U4H8 o;
            o.h[0] = (_Float16)r0; o.h[1] = (_Float16)r1;
            o.h[2] = (_Float16)r2; o.h[3] = (_Float16)r3;
            o.h[4] = (_Float16)r4; o.h[5] = (_Float16)r5;
            o.h[6] = (_Float16)r6; o.h[7] = (_Float16)r7;
            *(uint4*)(h_out + base) = o.u;
        }
    }
}

// ---------------- decode (fused LDS transpose of hF [N,64]) ----------------
__global__ __launch_bounds__(256) void decode_kernel(float* __restrict__ y,
                                                     const float* __restrict__ ctl,
                                                     const float* __restrict__ u,
                                                     const float* __restrict__ hF,
                                                     const float* __restrict__ W1,
                                                     const float* __restrict__ b1,
                                                     const float* __restrict__ W2,
                                                     const float* __restrict__ cell_dot) {
    __shared__ float tile[64][65];
    __shared__ float4 pack[HID];
    __shared__ float w2s[HID];
    __shared__ float cds[64];
    if (threadIdx.x < HID) {
        int hh = threadIdx.x;
        pack[hh] = make_float4(W1[0 * HID + hh], W1[1 * HID + hh], W1[2 * HID + hh], b1[hh]);
        w2s[hh] = W2[hh];
        cds[hh] = cell_dot[hh];
    }
    int n0 = blockIdx.x * 64;
    int tx = threadIdx.x & 63, ty = threadIdx.x >> 6;
#pragma unroll
    for (int i = 0; i < 16; ++i) {
        int n = n0 + ty + i * 4;
        tile[ty + i * 4][tx] = (n < N_NODES) ? hF[(size_t)n * 64 + tx] : 0.f;
    }
    __syncthreads();
#pragma unroll
    for (int i = 0; i < 16; ++i) {
        int b = ty + i * 4;
        int n = n0 + tx;
        if (n < N_NODES) {
            size_t idx = (size_t)b * N_NODES + n;
            float xc = ctl[idx], xu = u[idx], xh = tile[tx][b];
            float acc = 0.f;
#pragma unroll 8
            for (int hh = 0; hh < HID; ++hh) {
                float4 p = pack[hh];
                float t = fmaf(xc, p.x, fmaf(xu, p.y, fmaf(xh, p.z, p.w)));
                t = fmaxf(t, 0.f);
                acc = fmaf(t, w2s[hh], acc);
            }
            y[idx] = acc + cds[b];
        }
    }
}

// ---------------- launch ----------------
extern "C" void kernel_launch(void* const* d_in, const int* in_sizes, int n_in,
                              void* d_out, int out_size, void* d_ws, size_t ws_size,
                              hipStream_t stream) {
    const float* ctl          = (const float*)d_in[0];
    const float* u_raw        = (const float*)d_in[1];
    const int*   cell_idx     = (const int*)d_in[2];
    const int*   edge_src     = (const int*)d_in[3];
    const int*   edge_dst     = (const int*)d_in[4];
    const float* edge_val     = (const float*)d_in[5];
    const float* g_logits     = (const float*)d_in[6];
    const float* alpha_logits = (const float*)d_in[7];
    const float* cell_emb     = (const float*)d_in[8];
    const float* W1           = (const float*)d_in[9];
    const float* b1           = (const float*)d_in[10];
    const float* W2           = (const float*)d_in[11];
    const float* b2           = (const float*)d_in[12];
    float* y = (float*)d_out;

    const int TE = in_sizes[3];   // 6 * E
    const int E  = TE / 6;
    const int NB = N_NODES * 64;  // h elements

    char* ws = (char*)d_ws;
    size_t off = 0;
    auto alloc = [&](size_t bytes) -> char* {
        char* p = ws + off;
        off += (bytes + 255) & ~(size_t)255;
        return p;
    };
    int* grp_ptr = (int*)alloc((N_NODES + 1) * sizeof(int));
    int* counts  = (int*)alloc(N_NODES * sizeof(int));
    int* blksum  = (int*)alloc(CBLK * sizeof(int));
    int* blkcnt  = (int*)alloc((size_t)NSLICE * SUBB * SLICE_SZ * sizeof(int));
    int* gcnt    = (int*)alloc((size_t)NB1 * 8 * sizeof(int));
    int* blkoff  = (int*)alloc((size_t)NB1 * 8 * sizeof(int));
    int* bbase   = (int*)alloc(16 * sizeof(int));
    const size_t MAXG = (size_t)TE / 8 + N_NODES + 16;            // padded group bound
    unsigned* eg = (unsigned*)alloc(MAXG * 8 * sizeof(unsigned)); // 32 B/group
    // DISTINCT buffers (no aliasing): ws is 256 MB, total use ~60 MB
    int* bucketm    = (int*)alloc((size_t)TE * sizeof(int));
    int* bucketc    = (int*)alloc((size_t)TE * sizeof(int));
    _Float16* uh    = (_Float16*)alloc((size_t)NB * 2);
    _Float16* hA    = (_Float16*)alloc((size_t)NB * 2);
    _Float16* hB    = (_Float16*)alloc((size_t)NB * 2);
    float* hF       = (float*)alloc((size_t)NB * 4);
    float* gsign    = (float*)alloc(8 * sizeof(float));
    float* alph     = (float*)alloc(8 * sizeof(float));
    float* cell_dot = (float*)alloc(64 * sizeof(float));

    // 1. CSR build — edges read once, zero global atomics, XCD-local placement
    count8_kernel<<<NB1, 256, 0, stream>>>(edge_dst, gcnt, TE);
    scan8_kernel<<<1, 256, 0, stream>>>(gcnt, blkoff, bbase, g_logits, alpha_logits,
                                        cell_idx, cell_emb, W2, b2,
                                        gsign, alph, cell_dot);
    bucket_kernel<<<NB1, 256, 0, stream>>>(edge_src, edge_dst, edge_val, gsign,
                                           blkoff, bbase, bucketm, bucketc, E, TE);
    hist2db_kernel<<<NBLK, 256, 0, stream>>>(bucketm, bbase, blkcnt);
    colscan_kernel<<<CBLK, 256, 0, stream>>>(blkcnt, counts, blksum);
    scan2_kernel<<<CBLK, 256, 0, stream>>>(counts, blksum, grp_ptr, eg, N_NODES);
    // 2. placement + fused u transpose (uh f16 only)
    scatter2b_kernel<<<NBLK + TBLK, 256, 0, stream>>>(bucketm, bucketc, bbase, grp_ptr,
                                                      blkcnt, eg, u_raw, uh);

    // 3. 6 propagation steps: f16 ping-pong, fp32 final into hF
    const _Float16* hin = uh;
    for (int k = 0; k < NSTEPS; ++k) {
        _Float16* hout = (k & 1) ? hB : hA;
        step_kernel<<<(N_NODES + 3) / 4, 256, 0, stream>>>(hin, uh, hout, hF, grp_ptr,
                                                           eg, alph, k, k == NSTEPS - 1);
        hin = hout;
    }

    // 4. decode (reads hF [N,64] directly via LDS transpose)
    decode_kernel<<<TBLK, 256, 0, stream>>>(y, ctl, u_raw, hF, W1, b1, W2, cell_dot);
}

// Round 12
// 333.308 us; speedup vs baseline: 1.1737x; 1.1737x over previous
//
#include <hip/hip_runtime.h>

#define N_NODES 20000
#define HID 64
#define NSTEPS 6
#define NSLICE 8
#define SLICE_SZ (N_NODES / NSLICE)  // 2500
#define SUBB 64                      // sub-chunks per slice (phase 2)
#define NBLK (NSLICE * SUBB)         // 512 blocks for hist/scatter
#define TBLK ((N_NODES + 63) / 64)   // 313 transpose blocks (fused into scatter)
#define NB1 2048                     // blocks for count/bucket phase (8/CU: latency hiding)
#define CBLK ((N_NODES + 255) / 256) // 79 colscan/scan2 blocks
#define MAGIC 13422                  // floor(d*13422 / 2^25) == d/2500 for d < 20000

typedef _Float16 h8_t __attribute__((ext_vector_type(8)));
typedef float f4_t __attribute__((ext_vector_type(4)));  // native vec for nontemporal st

union U16H { unsigned short u; _Float16 h; };
union U4H8 { uint4 u; _Float16 h[8]; };

__device__ __forceinline__ _Float16 us_as_h(unsigned short s) { U16H u; u.u = s; return u.h; }
__device__ __forceinline__ unsigned short h_as_us(_Float16 h) { U16H u; u.h = h; return u.u; }

__device__ __forceinline__ int slice_of(int d) {
    return (int)(((unsigned)d * (unsigned)MAGIC) >> 25);
}
__device__ __forceinline__ float softplusf_(float x) {
    return (x > 0.f) ? (x + log1pf(expf(-x))) : log1pf(expf(x));
}
__device__ __forceinline__ float sigmoidf_(float x) {
    return 1.f / (1.f + expf(-x));
}

// ---------------- P0: per-(block,slice) edge counts ----------------
// Software-prefetched stream: next iteration's edst load issues before current's ballots.
// (eg zero-fill removed: pad slots are zeroed surgically in scan2 — ~280 KB not 9.8 MB.)
__global__ __launch_bounds__(256) void count8_kernel(const int* __restrict__ edst,
                                                     int* __restrict__ gcnt, int TE) {
    __shared__ int lh[8];
    int bk = blockIdx.x;
    int lane = threadIdx.x & 63;
    if (threadIdx.x < 8) lh[threadIdx.x] = 0;
    __syncthreads();
    int chunk = ((TE + NB1 - 1) / NB1 + 255) & ~255;
    int lo = bk * chunk;
    int hi = min(lo + chunk, TE);
    int my = 0;
    int i = lo + (int)threadIdx.x;
    bool act = i < hi;
    int d = 0;
    if (act) d = __builtin_nontemporal_load(edst + i);
    for (int ii = 0; ii < chunk; ii += 256) {
        int inext = i + 256;
        bool actn = inext < hi;
        int dn = 0;
        if (actn) dn = __builtin_nontemporal_load(edst + inext);  // prefetch next iter
        int s = act ? slice_of(d) : -1;
#pragma unroll
        for (int q = 0; q < 8; ++q) {
            unsigned long long b = __ballot(s == q);
            if (lane == q) my += (int)__popcll(b);
        }
        i = inext; act = actn; d = dn;
    }
    if (lane < 8) atomicAdd(&lh[lane], my);
    __syncthreads();
    if (threadIdx.x < 8) gcnt[bk * 8 + threadIdx.x] = lh[threadIdx.x];
}

// ---------------- P0b: scan gcnt -> blkoff + bbase[9]; fused prep constants ----------------
__global__ __launch_bounds__(256) void scan8_kernel(const int* __restrict__ gcnt,
                                                    int* __restrict__ blkoff,
                                                    int* __restrict__ bbase,
                                                    const float* __restrict__ g_logits,
                                                    const float* __restrict__ alpha_logits,
                                                    const int* __restrict__ cell_idx,
                                                    const float* __restrict__ cell_emb,
                                                    const float* __restrict__ W2,
                                                    const float* __restrict__ b2,
                                                    float* __restrict__ gsign,
                                                    float* __restrict__ alph,
                                                    float* __restrict__ cell_dot) {
    __shared__ int psum[8][33];
    int tid = threadIdx.x;
    int s = tid >> 5, g = tid & 31;
    const int per = NB1 / 32;  // 64
    int sum = 0;
    for (int b = g * per; b < (g + 1) * per; ++b) sum += gcnt[b * 8 + s];
    psum[s][g] = sum;
    __syncthreads();
    if (tid < 8) {
        int run = 0;
        for (int i = 0; i < 32; ++i) { int v = psum[tid][i]; psum[tid][i] = run; run += v; }
        psum[tid][32] = run;
    }
    __syncthreads();
    int run = psum[s][g];
    for (int b = g * per; b < (g + 1) * per; ++b) {
        blkoff[b * 8 + s] = run;
        run += gcnt[b * 8 + s];
    }
    if (tid == 0) {
        int acc = 0;
        bbase[0] = 0;
        for (int q = 0; q < 8; ++q) { acc += psum[q][32]; bbase[q + 1] = acc; }
    }
    // fused prep (independent outputs)
    if (tid < 64) {
        if (tid < 6) gsign[tid] = ((tid & 1) ? -1.f : 1.f) * softplusf_(g_logits[tid]);
        if (tid < NSTEPS) alph[tid] = sigmoidf_(alpha_logits[tid]);
        int ci = cell_idx[tid];
        float acc = b2[0];
        for (int hh = 0; hh < HID; ++hh) acc = fmaf(cell_emb[ci * HID + hh], W2[hh], acc);
        cell_dot[tid] = acc;
    }
}

// ---------------- P1: bucket edges by slice; SoA {meta, coef} ----------------
// Software-prefetched stream (same mechanism as count8). SoA so hist2db can
// read meta densely (AoS stride-2 read wasted half the line).
__global__ __launch_bounds__(256) void bucket_kernel(const int* __restrict__ esrc,
                                                     const int* __restrict__ edst,
                                                     const float* __restrict__ eval,
                                                     const float* __restrict__ gsign,
                                                     const int* __restrict__ blkoff,
                                                     const int* __restrict__ bbase,
                                                     int* __restrict__ bucketm,
                                                     int* __restrict__ bucketc,
                                                     int E, int TE) {
    __shared__ int lcur[8];
    int bk = blockIdx.x;
    int lane = threadIdx.x & 63;
    if (threadIdx.x < 8) lcur[threadIdx.x] = bbase[threadIdx.x] + blkoff[bk * 8 + threadIdx.x];
    __syncthreads();
    int chunk = ((TE + NB1 - 1) / NB1 + 255) & ~255;
    int lo = bk * chunk;
    int hi = min(lo + chunk, TE);
    int i = lo + (int)threadIdx.x;
    bool act = i < hi;
    int d = 0, sv = 0;
    float ev = 0.f;
    if (act) {
        d  = __builtin_nontemporal_load(edst + i);
        sv = __builtin_nontemporal_load(esrc + i);
        ev = __builtin_nontemporal_load(eval + i);
    }
    for (int ii = 0; ii < chunk; ii += 256) {
        // issue next iteration's loads before consuming current (hide stream latency)
        int inext = i + 256;
        bool actn = inext < hi;
        int dn = 0, svn = 0;
        float evn = 0.f;
        if (actn) {
            dn  = __builtin_nontemporal_load(edst + inext);
            svn = __builtin_nontemporal_load(esrc + inext);
            evn = __builtin_nontemporal_load(eval + inext);
        }
        int s = -1, meta = 0, cb = 0;
        if (act) {
            s = slice_of(d);
            int dl = d - s * SLICE_SZ;
            meta = sv | (dl << 16);
            int r = (i >= E) + (i >= 2 * E) + (i >= 3 * E) + (i >= 4 * E) + (i >= 5 * E);
            cb = __float_as_int(gsign[r] * ev);
        }
        int pos = 0;
#pragma unroll
        for (int q = 0; q < 8; ++q) {
            unsigned long long b = __ballot(s == q);
            if (b) {
                int leader = (int)__ffsll(b) - 1;
                int base = 0;
                if (lane == leader) base = atomicAdd(&lcur[q], (int)__popcll(b));
                base = __shfl(base, leader);
                if (s == q) pos = base + (int)__popcll(b & ((1ull << lane) - 1ull));
            }
        }
        if (act) {
            bucketm[pos] = meta;
            bucketc[pos] = cb;
        }
        i = inext; act = actn; d = dn; sv = svn; ev = evn;
    }
}

// ---------------- P2: per-(slice,sub) LDS histogram from the bucket (dense meta) --------
__global__ __launch_bounds__(256) void hist2db_kernel(const int* __restrict__ bucketm,
                                                      const int* __restrict__ bbase,
                                                      int* __restrict__ blkcnt) {
    __shared__ int lh[SLICE_SZ];
    int bk = blockIdx.x;
    int slice = bk & (NSLICE - 1);
    int sub = bk >> 3;
    for (int b = threadIdx.x; b < SLICE_SZ; b += 256) lh[b] = 0;
    __syncthreads();
    int lo = bbase[slice];
    int total = bbase[slice + 1] - lo;
    int chunk = ((total + SUBB - 1) / SUBB + 255) & ~255;
    int beg = lo + sub * chunk;
    int end = min(beg + chunk, lo + total);
    for (int i = beg + (int)threadIdx.x; i < end; i += 256) {
        int meta = __builtin_nontemporal_load(bucketm + i);
        atomicAdd(&lh[((unsigned)meta) >> 16], 1);
    }
    __syncthreads();
    int* out = blkcnt + (size_t)(slice * SUBB + sub) * SLICE_SZ;
    for (int b = threadIdx.x; b < SLICE_SZ; b += 256) out[b] = lh[b];
}

// ---------------- P3a: per-bin prefix across sub-blocks + per-block group sums ----------------
__global__ __launch_bounds__(256) void colscan_kernel(int* __restrict__ blkcnt,
                                                      int* __restrict__ counts,
                                                      int* __restrict__ blksum) {
    int n = blockIdx.x * 256 + threadIdx.x;
    int run = 0;
    if (n < N_NODES) {
        int slice = n / SLICE_SZ, bin = n % SLICE_SZ;
        size_t base = (size_t)slice * SUBB * SLICE_SZ + bin;
#pragma unroll 8
        for (int s = 0; s < SUBB; ++s) {
            size_t idx = base + (size_t)s * SLICE_SZ;
            int t = blkcnt[idx];
            blkcnt[idx] = run;
            run += t;
        }
        counts[n] = run;
    }
    // fused: block sum of padded group counts -> blksum[blockIdx.x]
    int g = (n < N_NODES) ? ((run + 7) >> 3) : 0;
#pragma unroll
    for (int st = 1; st < 64; st <<= 1) g += __shfl_xor(g, st, 64);
    __shared__ int wsum[4];
    if ((threadIdx.x & 63) == 0) wsum[threadIdx.x >> 6] = g;
    __syncthreads();
    if (threadIdx.x == 0) blksum[blockIdx.x] = wsum[0] + wsum[1] + wsum[2] + wsum[3];
}

// ---------------- P3b: parallel scan -> grp_ptr + surgical eg pad-zeroing ----------------
__global__ __launch_bounds__(256) void scan2_kernel(const int* __restrict__ counts,
                                                    const int* __restrict__ blksum,
                                                    int* __restrict__ grp_ptr,
                                                    unsigned* __restrict__ eg, int n) {
    int b = blockIdx.x;
    int tid = threadIdx.x, lane = tid & 63, wid = tid >> 6;
    int i = b * 256 + tid;
    int c = (i < n) ? counts[i] : 0;
    int v = (c + 7) >> 3;  // groups for this node
    int x = v;
#pragma unroll
    for (int st = 1; st < 64; st <<= 1) {
        int t = __shfl_up(x, st, 64);
        if (lane >= st) x += t;
    }
    __shared__ int wsum[4];
    if (lane == 63) wsum[wid] = x;
    // global offset: sum of blksum[l < b], redundant per wave (CBLK=79 < 128)
    int s = ((lane < b) ? blksum[lane] : 0) +
            ((lane + 64 < b) ? blksum[lane + 64] : 0);
#pragma unroll
    for (int st = 1; st < 64; st <<= 1) s += __shfl_xor(s, st, 64);
    __syncthreads();
    int woff = s;
    if (wid > 0) woff += wsum[0];
    if (wid > 1) woff += wsum[1];
    if (wid > 2) woff += wsum[2];
    int off = woff + x - v;  // exclusive
    if (i < n) {
        grp_ptr[i] = off;
        // zero ONLY the pad slots of this node's last group (<=7 entries);
        // step kernels never read past grp_ptr[i+1] so nothing else needs zeroing
        unsigned* base = eg + (size_t)off * 8;
        int slots = v * 8;
        for (int p = c; p < slots; ++p) base[p] = 0u;
    }
    if (i == n - 1) grp_ptr[n] = off + v;
}

// ---------------- P4: placement into 8-edge groups; fused u-transpose ----------------
// Group g: eg[8g + s] = src | (coef_f16 << 16), s=0..7. Pad slots zeroed by scan2.
// NOTE: uh must NOT alias buckets — transpose blocks run concurrently with
// scatter blocks inside this single launch.
__global__ __launch_bounds__(256) void scatter2b_kernel(const int* __restrict__ bucketm,
                                                        const int* __restrict__ bucketc,
                                                        const int* __restrict__ bbase,
                                                        const int* __restrict__ grp_ptr,
                                                        const int* __restrict__ blkcnt,
                                                        unsigned* __restrict__ eg,
                                                        const float* __restrict__ u_raw,
                                                        _Float16* __restrict__ uh) {
    __shared__ float smem[64 * 65];  // union: lbase (10 KB) | transpose tile (16.6 KB)
    int bk = blockIdx.x;
    if (bk >= NBLK) {
        // --- transpose section: u_raw [64, N] -> uh [N, 64] (f16) ---
        float(*tile)[65] = (float(*)[65])smem;
        int c0 = (bk - NBLK) * 64;
        int tx = threadIdx.x & 63, ty = threadIdx.x >> 6;
#pragma unroll
        for (int i = 0; i < 16; ++i) {
            int c = c0 + tx;
            tile[ty + i * 4][tx] = (c < N_NODES) ? u_raw[(size_t)(ty + i * 4) * N_NODES + c] : 0.f;
        }
        __syncthreads();
#pragma unroll
        for (int i = 0; i < 16; ++i) {
            int c = c0 + ty + i * 4;
            if (c < N_NODES) {
                float v = tile[tx][ty + i * 4];
                uh[(size_t)c * 64 + tx] = (_Float16)v;
            }
        }
        return;
    }
    int* lbase = (int*)smem;
    int slice = bk & (NSLICE - 1);
    int sub = bk >> 3;
    int lo_n = slice * SLICE_SZ;
    const int* boff = blkcnt + (size_t)(slice * SUBB + sub) * SLICE_SZ;
    for (int b = threadIdx.x; b < SLICE_SZ; b += 256)
        lbase[b] = grp_ptr[lo_n + b] * 8 + boff[b];
    __syncthreads();
    int lo = bbase[slice];
    int total = bbase[slice + 1] - lo;
    int chunk = ((total + SUBB - 1) / SUBB + 255) & ~255;
    int beg = lo + sub * chunk;
    int end = min(beg + chunk, lo + total);
    for (int i = beg + (int)threadIdx.x; i < end; i += 256) {
        int meta = __builtin_nontemporal_load(bucketm + i);
        float cf = __int_as_float(__builtin_nontemporal_load(bucketc + i));
        int pos = atomicAdd(&lbase[((unsigned)meta) >> 16], 1);
        eg[pos] = (unsigned)(meta & 0xFFFF) | ((unsigned)h_as_us((_Float16)cf) << 16);
    }
}

// ---------------- propagation step: 8 edges/gather, 4-group software pipeline ----------------
// R9-verbatim (334.2 us best). Wave = 1 node. Lane L: edge slot (L>>3) of each group,
// batch octet (L&7)*8..+8 — a wave's gather of one edge = one 128B line, L1-coalesced.
// eg entry loads CACHED (cross-step L2 reuse; R6: nt cost +28us).
// Refuted levers: depth-2 pipeline (R2 +11, R8 +18), L1 bypass (R10 +57), nt eg (R6 +28).
__global__ __launch_bounds__(256) void step_kernel(const _Float16* __restrict__ h_in,
                                                   const _Float16* __restrict__ h0,
                                                   _Float16* __restrict__ h_out,
                                                   float* __restrict__ hF,
                                                   const int* __restrict__ grp_ptr,
                                                   const unsigned* __restrict__ eg,
                                                   const float* __restrict__ alph,
                                                   int k, int last) {
    int lane = threadIdx.x & 63;
    int node = blockIdx.x * 4 + (threadIdx.x >> 6);
    if (node >= N_NODES) return;
    int gb = __builtin_amdgcn_readfirstlane(grp_ptr[node]);
    int ge = __builtin_amdgcn_readfirstlane(grp_ptr[node + 1]);
    int sub8 = lane >> 3;
    const _Float16* hbase = h_in + (lane & 7) * 8;
    const unsigned* ep = eg + sub8;
    float acc[8] = {0.f, 0.f, 0.f, 0.f, 0.f, 0.f, 0.f, 0.f};
    int g = gb;
    unsigned e0, e1, e2, e3;
    if (g + 4 <= ge) {
        e0 = ep[(size_t)g * 8];
        e1 = ep[(size_t)g * 8 + 8];
        e2 = ep[(size_t)g * 8 + 16];
        e3 = ep[(size_t)g * 8 + 24];
    }
    for (; g + 8 <= ge; g += 4) {
        // gathers for current quad
        h8_t v0 = *(const h8_t*)(hbase + (e0 & 0xFFFFu) * 64);
        h8_t v1 = *(const h8_t*)(hbase + (e1 & 0xFFFFu) * 64);
        h8_t v2 = *(const h8_t*)(hbase + (e2 & 0xFFFFu) * 64);
        h8_t v3 = *(const h8_t*)(hbase + (e3 & 0xFFFFu) * 64);
        // prefetch next quad's entries (independent of gathers)
        unsigned f0 = ep[(size_t)(g + 4) * 8];
        unsigned f1 = ep[(size_t)(g + 4) * 8 + 8];
        unsigned f2 = ep[(size_t)(g + 4) * 8 + 16];
        unsigned f3 = ep[(size_t)(g + 4) * 8 + 24];
        float c0 = (float)us_as_h((unsigned short)(e0 >> 16));
        float c1 = (float)us_as_h((unsigned short)(e1 >> 16));
        float c2 = (float)us_as_h((unsigned short)(e2 >> 16));
        float c3 = (float)us_as_h((unsigned short)(e3 >> 16));
#pragma unroll
        for (int j = 0; j < 8; ++j) acc[j] = fmaf((float)v0[j], c0, acc[j]);
#pragma unroll
        for (int j = 0; j < 8; ++j) acc[j] = fmaf((float)v1[j], c1, acc[j]);
#pragma unroll
        for (int j = 0; j < 8; ++j) acc[j] = fmaf((float)v2[j], c2, acc[j]);
#pragma unroll
        for (int j = 0; j < 8; ++j) acc[j] = fmaf((float)v3[j], c3, acc[j]);
        e0 = f0; e1 = f1; e2 = f2; e3 = f3;
    }
    if (g + 4 <= ge) {  // final full quad (entries already in registers)
        h8_t v0 = *(const h8_t*)(hbase + (e0 & 0xFFFFu) * 64);
        h8_t v1 = *(const h8_t*)(hbase + (e1 & 0xFFFFu) * 64);
        h8_t v2 = *(const h8_t*)(hbase + (e2 & 0xFFFFu) * 64);
        h8_t v3 = *(const h8_t*)(hbase + (e3 & 0xFFFFu) * 64);
        float c0 = (float)us_as_h((unsigned short)(e0 >> 16));
        float c1 = (float)us_as_h((unsigned short)(e1 >> 16));
        float c2 = (float)us_as_h((unsigned short)(e2 >> 16));
        float c3 = (float)us_as_h((unsigned short)(e3 >> 16));
#pragma unroll
        for (int j = 0; j < 8; ++j) acc[j] = fmaf((float)v0[j], c0, acc[j]);
#pragma unroll
        for (int j = 0; j < 8; ++j) acc[j] = fmaf((float)v1[j], c1, acc[j]);
#pragma unroll
        for (int j = 0; j < 8; ++j) acc[j] = fmaf((float)v2[j], c2, acc[j]);
#pragma unroll
        for (int j = 0; j < 8; ++j) acc[j] = fmaf((float)v3[j], c3, acc[j]);
        g += 4;
    }
    for (; g < ge; ++g) {
        unsigned e = ep[(size_t)g * 8];
        h8_t v = *(const h8_t*)(hbase + (e & 0xFFFFu) * 64);
        float c = (float)us_as_h((unsigned short)(e >> 16));
#pragma unroll
        for (int j = 0; j < 8; ++j) acc[j] = fmaf((float)v[j], c, acc[j]);
    }
    // reduce edge slots: lanes {c, c+8, ..., c+56} share a batch octet
#pragma unroll
    for (int st = 8; st < 64; st <<= 1) {
#pragma unroll
        for (int j = 0; j < 8; ++j) acc[j] += __shfl_xor(acc[j], st, 64);
    }
    if (lane < 8) {
        float a = alph[k];
        int base = node * 64 + lane * 8;
        U4H8 hv;
        hv.u = *(const uint4*)(h0 + base);  // h0 in f16 (uh)
        float om = 1.f - a;
        float r0 = fmaf(a, (float)hv.h[0], om * acc[0]);
        float r1 = fmaf(a, (float)hv.h[1], om * acc[1]);
        float r2 = fmaf(a, (float)hv.h[2], om * acc[2]);
        float r3 = fmaf(a, (float)hv.h[3], om * acc[3]);
        float r4 = fmaf(a, (float)hv.h[4], om * acc[4]);
        float r5 = fmaf(a, (float)hv.h[5], om * acc[5]);
        float r6 = fmaf(a, (float)hv.h[6], om * acc[6]);
        float r7 = fmaf(a, (float)hv.h[7], om * acc[7]);
        if (last) {
            // hF is written once, read once (decode) — keep it out of L2
            f4_t o0 = {r0, r1, r2, r3};
            f4_t o1 = {r4, r5, r6, r7};
            __builtin_nontemporal_store(o0, (f4_t*)(hF + base));
            __builtin_nontemporal_store(o1, (f4_t*)(hF + base + 4));
        } else {
            U4H8 o;
            o.h[0] = (_Float16)r0; o.h[1] = (_Float16)r1;
            o.h[2] = (_Float16)r2; o.h[3] = (_Float16)r3;
            o.h[4] = (_Float16)r4; o.h[5] = (_Float16)r5;
            o.h[6] = (_Float16)r6; o.h[7] = (_Float16)r7;
            *(uint4*)(h_out + base) = o.u;
        }
    }
}

// ---------------- decode (fused LDS transpose of hF [N,64]) ----------------
__global__ __launch_bounds__(256) void decode_kernel(float* __restrict__ y,
                                                     const float* __restrict__ ctl,
                                                     const float* __restrict__ u,
                                                     const float* __restrict__ hF,
                                                     const float* __restrict__ W1,
                                                     const float* __restrict__ b1,
                                                     const float* __restrict__ W2,
                                                     const float* __restrict__ cell_dot) {
    __shared__ float tile[64][65];
    __shared__ float4 pack[HID];
    __shared__ float w2s[HID];
    __shared__ float cds[64];
    if (threadIdx.x < HID) {
        int hh = threadIdx.x;
        pack[hh] = make_float4(W1[0 * HID + hh], W1[1 * HID + hh], W1[2 * HID + hh], b1[hh]);
        w2s[hh] = W2[hh];
        cds[hh] = cell_dot[hh];
    }
    int n0 = blockIdx.x * 64;
    int tx = threadIdx.x & 63, ty = threadIdx.x >> 6;
#pragma unroll
    for (int i = 0; i < 16; ++i) {
        int n = n0 + ty + i * 4;
        tile[ty + i * 4][tx] = (n < N_NODES) ? hF[(size_t)n * 64 + tx] : 0.f;
    }
    __syncthreads();
#pragma unroll
    for (int i = 0; i < 16; ++i) {
        int b = ty + i * 4;
        int n = n0 + tx;
        if (n < N_NODES) {
            size_t idx = (size_t)b * N_NODES + n;
            float xc = ctl[idx], xu = u[idx], xh = tile[tx][b];
            float acc = 0.f;
#pragma unroll 8
            for (int hh = 0; hh < HID; ++hh) {
                float4 p = pack[hh];
                float t = fmaf(xc, p.x, fmaf(xu, p.y, fmaf(xh, p.z, p.w)));
                t = fmaxf(t, 0.f);
                acc = fmaf(t, w2s[hh], acc);
            }
            y[idx] = acc + cds[b];
        }
    }
}

// ---------------- launch ----------------
extern "C" void kernel_launch(void* const* d_in, const int* in_sizes, int n_in,
                              void* d_out, int out_size, void* d_ws, size_t ws_size,
                              hipStream_t stream) {
    const float* ctl          = (const float*)d_in[0];
    const float* u_raw        = (const float*)d_in[1];
    const int*   cell_idx     = (const int*)d_in[2];
    const int*   edge_src     = (const int*)d_in[3];
    const int*   edge_dst     = (const int*)d_in[4];
    const float* edge_val     = (const float*)d_in[5];
    const float* g_logits     = (const float*)d_in[6];
    const float* alpha_logits = (const float*)d_in[7];
    const float* cell_emb     = (const float*)d_in[8];
    const float* W1           = (const float*)d_in[9];
    const float* b1           = (const float*)d_in[10];
    const float* W2           = (const float*)d_in[11];
    const float* b2           = (const float*)d_in[12];
    float* y = (float*)d_out;

    const int TE = in_sizes[3];   // 6 * E
    const int E  = TE / 6;
    const int NB = N_NODES * 64;  // h elements

    char* ws = (char*)d_ws;
    size_t off = 0;
    auto alloc = [&](size_t bytes) -> char* {
        char* p = ws + off;
        off += (bytes + 255) & ~(size_t)255;
        return p;
    };
    int* grp_ptr = (int*)alloc((N_NODES + 1) * sizeof(int));
    int* counts  = (int*)alloc(N_NODES * sizeof(int));
    int* blksum  = (int*)alloc(CBLK * sizeof(int));
    int* blkcnt  = (int*)alloc((size_t)NSLICE * SUBB * SLICE_SZ * sizeof(int));
    int* gcnt    = (int*)alloc((size_t)NB1 * 8 * sizeof(int));
    int* blkoff  = (int*)alloc((size_t)NB1 * 8 * sizeof(int));
    int* bbase   = (int*)alloc(16 * sizeof(int));
    const size_t MAXG = (size_t)TE / 8 + N_NODES + 16;            // padded group bound
    unsigned* eg = (unsigned*)alloc(MAXG * 8 * sizeof(unsigned)); // 32 B/group
    // DISTINCT buffers (no aliasing): ws is 256 MB, total use ~60 MB
    int* bucketm    = (int*)alloc((size_t)TE * sizeof(int));
    int* bucketc    = (int*)alloc((size_t)TE * sizeof(int));
    _Float16* uh    = (_Float16*)alloc((size_t)NB * 2);
    _Float16* hA    = (_Float16*)alloc((size_t)NB * 2);
    _Float16* hB    = (_Float16*)alloc((size_t)NB * 2);
    float* hF       = (float*)alloc((size_t)NB * 4);
    float* gsign    = (float*)alloc(8 * sizeof(float));
    float* alph     = (float*)alloc(8 * sizeof(float));
    float* cell_dot = (float*)alloc(64 * sizeof(float));

    // 1. CSR build — edges read once, zero global atomics, XCD-local placement
    count8_kernel<<<NB1, 256, 0, stream>>>(edge_dst, gcnt, TE);
    scan8_kernel<<<1, 256, 0, stream>>>(gcnt, blkoff, bbase, g_logits, alpha_logits,
                                        cell_idx, cell_emb, W2, b2,
                                        gsign, alph, cell_dot);
    bucket_kernel<<<NB1, 256, 0, stream>>>(edge_src, edge_dst, edge_val, gsign,
                                           blkoff, bbase, bucketm, bucketc, E, TE);
    hist2db_kernel<<<NBLK, 256, 0, stream>>>(bucketm, bbase, blkcnt);
    colscan_kernel<<<CBLK, 256, 0, stream>>>(blkcnt, counts, blksum);
    scan2_kernel<<<CBLK, 256, 0, stream>>>(counts, blksum, grp_ptr, eg, N_NODES);
    // 2. placement + fused u transpose (uh f16 only)
    scatter2b_kernel<<<NBLK + TBLK, 256, 0, stream>>>(bucketm, bucketc, bbase, grp_ptr,
                                                      blkcnt, eg, u_raw, uh);

    // 3. 6 propagation steps: f16 ping-pong, fp32 final into hF
    const _Float16* hin = uh;
    for (int k = 0; k < NSTEPS; ++k) {
        _Float16* hout = (k & 1) ? hB : hA;
        step_kernel<<<(N_NODES + 3) / 4, 256, 0, stream>>>(hin, uh, hout, hF, grp_ptr,
                                                           eg, alph, k, k == NSTEPS - 1);
        hin = hout;
    }

    // 4. decode (reads hF [N,64] directly via LDS transpose)
    decode_kernel<<<TBLK, 256, 0, stream>>>(y, ctl, u_raw, hF, W1, b1, W2, cell_dot);
}